// Round 1
// baseline (595.377 us; speedup 1.0000x reference)
//
#include <hip/hip_runtime.h>
#include <hip/hip_bf16.h>
#include <cstdint>
#include <cstddef>

// Problem shape (fixed by reference): B=8, N=1024, D=768, H=12, dh=64, 3 branches
#define B_   8
#define N_   1024
#define D_   768
#define H_   12
#define DH_  64
#define M_   (B_ * N_)          // 8192 rows
#define WSZ_ (D_ * D_)          // 589824 per weight matrix

typedef __bf16 bf16;
typedef bf16  bf16x8  __attribute__((ext_vector_type(8)));
typedef bf16  bf16x4  __attribute__((ext_vector_type(4)));
typedef float floatx4 __attribute__((ext_vector_type(4)));

// ---------------------------------------------------------------------------
// async global->LDS, 16B per lane (wave-uniform LDS base + lane*16)
__device__ __forceinline__ void gload_lds16(const void* g, void* l) {
    __builtin_amdgcn_global_load_lds(
        (const __attribute__((address_space(1))) unsigned int*)g,
        (__attribute__((address_space(3))) unsigned int*)l, 16, 0, 0);
}

// ---------------------------------------------------------------------------
// Kernel 1: per-row norm -> branch scales; x -> bf16.
// All three branch inputs are row-wise scalar multiples of x:
//   x_e = 1*x ; x_h = s_h*x (expmap0+project) ; x_s = s_s*x (logmap0)
__global__ __launch_bounds__(256) void prep_x(const float* __restrict__ x,
                                              bf16* __restrict__ xbf,
                                              float* __restrict__ sc /* [2][M_] */) {
    int row = blockIdx.x;
    int tid = threadIdx.x;
    const float* xr = x + (size_t)row * D_;
    bf16* xo = xbf + (size_t)row * D_;
    float v0 = xr[tid], v1 = xr[tid + 256], v2 = xr[tid + 512];
    xo[tid]       = (bf16)v0;
    xo[tid + 256] = (bf16)v1;
    xo[tid + 512] = (bf16)v2;
    float ss = v0 * v0 + v1 * v1 + v2 * v2;
    for (int off = 32; off; off >>= 1) ss += __shfl_xor(ss, off, 64);
    __shared__ float red[4];
    if ((tid & 63) == 0) red[tid >> 6] = ss;
    __syncthreads();
    if (tid == 0) {
        float t2 = red[0] + red[1] + red[2] + red[3];
        float t  = sqrtf(t2);                       // true ||x||
        const float scst = 0.31622776601683794f;    // sqrt(0.1)
        float un = fmaxf(t, 1e-5f);
        // expmap0 scale
        float s1 = tanhf(scst * un) / (scst * un);
        // project
        float nh = fmaxf(t * s1, 1e-5f);
        float maxnorm = (1.0f - 4e-3f) / scst;
        float sh = (nh > maxnorm) ? s1 * (maxnorm / nh) : s1;
        // logmap0 scale
        float arg = fminf(scst * un, 1.0f - 1e-5f);
        float artanh = 0.5f * logf((1.0f + arg) / (1.0f - arg));
        float ssc = artanh / (un * scst);
        sc[row]      = sh;
        sc[M_ + row] = ssc;
    }
}

// ---------------------------------------------------------------------------
// Kernel 2: weights fp32 -> bf16, layout wbf[branch][t][o][k], t: 0=q,1=k,2=v
__global__ __launch_bounds__(256) void prep_w(const float* __restrict__ wq,
                                              const float* __restrict__ wk,
                                              const float* __restrict__ wv,
                                              bf16* __restrict__ wbf) {
    size_t i = ((size_t)blockIdx.x * 256 + threadIdx.x) * 4;  // 9*WSZ_ total
    int z = (int)(i / WSZ_);
    int r = (int)(i % WSZ_);
    int branch = z / 3, t = z % 3;
    const float* src = (t == 0 ? wq : t == 1 ? wk : wv) + (size_t)branch * WSZ_ + r;
    float4 f = *(const float4*)src;
    bf16x4 o = { (bf16)f.x, (bf16)f.y, (bf16)f.z, (bf16)f.w };
    *(bf16x4*)(wbf + i) = o;
}

// ---------------------------------------------------------------------------
// Kernel 3: Y = x @ W^T, epilogue y = s_branch[row]*y + bias[col] -> bf16 qkv
// m97 structure: 128x128 tile, BK=32, 4 waves each 64x64 (4x4 of 16x16x32 MFMA)
#define BM 128
#define BN 128
#define BK 32
__global__ __launch_bounds__(256) void gemm_qkv(
        const bf16* __restrict__ xbf, const bf16* __restrict__ wbf_all,
        const float* __restrict__ bq, const float* __restrict__ bk,
        const float* __restrict__ bv, const float* __restrict__ sc,
        int branch, bf16* __restrict__ qkv) {
    int t = blockIdx.z;
    const bf16*  wsrc = wbf_all + (size_t)(branch * 3 + t) * WSZ_;
    const float* bias = (t == 0 ? bq : t == 1 ? bk : bv) + branch * D_;
    bf16* out = qkv + (size_t)t * M_ * D_;
    int bm0 = blockIdx.y * BM;
    int bn0 = blockIdx.x * BN;

    __shared__ bf16 lA[BM * BK];   // 8 KB
    __shared__ bf16 lB[BN * BK];   // 8 KB

    int tid = threadIdx.x;
    int w = tid >> 6, lane = tid & 63;
    int wr = w >> 1, wc = w & 1;
    int quad = lane >> 4, c15 = lane & 15;
    int lrow = lane >> 2;           // 0..15 within a 16-row chunk
    int lcol = (lane & 3) * 8;      // k offset 0/8/16/24

    floatx4 acc[4][4];
    for (int i = 0; i < 4; i++)
        for (int j = 0; j < 4; j++)
            acc[i][j] = (floatx4){0.f, 0.f, 0.f, 0.f};

    for (int k0 = 0; k0 < D_; k0 += BK) {
        // stage A,B tiles: each wave 2+2 width-16 global_load_lds (1 KB each)
        const bf16* ga = xbf  + ((size_t)(bm0 + w * 32 + lrow) * D_ + k0 + lcol);
        const bf16* gb = wsrc + ((size_t)(bn0 + w * 32 + lrow) * D_ + k0 + lcol);
        gload_lds16(ga,           (char*)lA + w * 2048);
        gload_lds16(ga + 16 * D_, (char*)lA + w * 2048 + 1024);
        gload_lds16(gb,           (char*)lB + w * 2048);
        gload_lds16(gb + 16 * D_, (char*)lB + w * 2048 + 1024);
        __syncthreads();

        int arow = wr * 64 + c15;
        int brow = wc * 64 + c15;
        int kq = quad * 8;
        bf16x8 af[4], bfm[4];
        for (int i = 0; i < 4; i++) af[i]  = *(const bf16x8*)(lA + (arow + i * 16) * BK + kq);
        for (int j = 0; j < 4; j++) bfm[j] = *(const bf16x8*)(lB + (brow + j * 16) * BK + kq);
        for (int i = 0; i < 4; i++)
            for (int j = 0; j < 4; j++)
                acc[i][j] = __builtin_amdgcn_mfma_f32_16x16x32_bf16(af[i], bfm[j], acc[i][j], 0, 0, 0);
        __syncthreads();
    }

    // epilogue: y = s[row]*y + bias[col]
    const float* scb = (branch == 0) ? nullptr : sc + (size_t)(branch - 1) * M_;
    float bj[4];
    for (int j = 0; j < 4; j++) bj[j] = bias[bn0 + wc * 64 + j * 16 + c15];
    for (int i = 0; i < 4; i++) {
        int gRow0 = bm0 + wr * 64 + i * 16 + quad * 4;
        for (int r = 0; r < 4; r++) {
            float s = scb ? scb[gRow0 + r] : 1.0f;
            bf16* orow = out + (size_t)(gRow0 + r) * D_;
            for (int j = 0; j < 4; j++) {
                int gCol = bn0 + wc * 64 + j * 16 + c15;
                orow[gCol] = (bf16)(s * acc[i][j][r] + bj[j]);
            }
        }
    }
}

// ---------------------------------------------------------------------------
// Kernel 4: flash attention for one branch, accumulating into fp32 out.
// Block = (q-tile of 64) x (batch,head). 4 waves, each 16 q-rows.
#define LDK 72   // padded LDS stride (72*2B = 144B, 16B-aligned rows)
__global__ __launch_bounds__(256) void attn(const bf16* __restrict__ qkv,
                                            float* __restrict__ out,
                                            int accumulate) {
    int qt = blockIdx.x;              // 0..15
    int bh = blockIdx.y;              // 0..95
    int batch = bh / H_, head = bh % H_;
    int n0 = qt * 64;
    int tid = threadIdx.x, w = tid >> 6, lane = tid & 63;
    int quad = lane >> 4, c15 = lane & 15;

    const bf16* qb = qkv;
    const bf16* kb = qkv + (size_t)M_ * D_;
    const bf16* vb = qkv + (size_t)2 * M_ * D_;
    size_t baseRow = (size_t)batch * N_;
    int colOff = head * DH_;

    __shared__ bf16 sK[64 * LDK];        // K tile [key][d]
    __shared__ bf16 sVt[64 * LDK];       // V tile transposed [d][key]
    __shared__ bf16 sP[4][16 * LDK];     // per-wave P [q][key]

    // Q A-fragments, held in registers for the whole block
    int qrow = n0 + w * 16 + c15;
    bf16x8 aq0, aq1;
    {
        const bf16* qp = qb + ((baseRow + qrow) * D_ + colOff + quad * 8);
        aq0 = *(const bf16x8*)qp;
        aq1 = *(const bf16x8*)(qp + 32);
    }

    float m_i[4], l_i[4];
    floatx4 o_acc[4];
    for (int r = 0; r < 4; r++) { m_i[r] = -3.0e38f; l_i[r] = 0.f; }
    for (int j = 0; j < 4; j++) o_acc[j] = (floatx4){0.f, 0.f, 0.f, 0.f};

    for (int kt = 0; kt < 16; kt++) {
        int m0 = kt * 64;
        // stage K [64][64] row-major (vector 16B loads+stores)
        for (int c = tid; c < 512; c += 256) {
            int key = c >> 3, dcol = (c & 7) << 3;
            *(bf16x8*)(sK + key * LDK + dcol) =
                *(const bf16x8*)(kb + (baseRow + m0 + key) * D_ + colOff + dcol);
        }
        // stage V transposed [d][key]
        {
            int key = tid >> 2, d0 = (tid & 3) << 4;
            const bf16* vp = vb + (baseRow + m0 + key) * D_ + colOff + d0;
            bf16x8 v0 = *(const bf16x8*)vp;
            bf16x8 v1 = *(const bf16x8*)(vp + 8);
            for (int i = 0; i < 8; i++) sVt[(d0 + i) * LDK + key]     = v0[i];
            for (int i = 0; i < 8; i++) sVt[(d0 + 8 + i) * LDK + key] = v1[i];
        }
        __syncthreads();

        // S = Q K^T  (4 frags of 16x16 over the 64 keys)
        floatx4 sfr[4];
        for (int j = 0; j < 4; j++) {
            const bf16* kp = sK + (j * 16 + c15) * LDK + quad * 8;
            bf16x8 b0 = *(const bf16x8*)kp;
            bf16x8 b1 = *(const bf16x8*)(kp + 32);
            floatx4 z = (floatx4){0.f, 0.f, 0.f, 0.f};
            z = __builtin_amdgcn_mfma_f32_16x16x32_bf16(aq0, b0, z, 0, 0, 0);
            z = __builtin_amdgcn_mfma_f32_16x16x32_bf16(aq1, b1, z, 0, 0, 0);
            sfr[j] = z;
        }

        // online softmax (row = quad*4+r, 16 key-lanes per frag)
        float mnew[4], rs[4];
        for (int r = 0; r < 4; r++) {
            float mx = fmaxf(fmaxf(sfr[0][r], sfr[1][r]), fmaxf(sfr[2][r], sfr[3][r]));
            for (int msk = 1; msk < 16; msk <<= 1) mx = fmaxf(mx, __shfl_xor(mx, msk, 64));
            mnew[r] = fmaxf(m_i[r], mx);
        }
        for (int r = 0; r < 4; r++) {
            float sum = 0.f;
            for (int j = 0; j < 4; j++) {
                float p = __expf(sfr[j][r] - mnew[r]);
                sfr[j][r] = p;
                sum += p;
            }
            for (int msk = 1; msk < 16; msk <<= 1) sum += __shfl_xor(sum, msk, 64);
            rs[r] = sum;
        }
        for (int r = 0; r < 4; r++) {
            float alpha = __expf(m_i[r] - mnew[r]);
            l_i[r] = alpha * l_i[r] + rs[r];
            m_i[r] = mnew[r];
            for (int j = 0; j < 4; j++) o_acc[j][r] *= alpha;
        }

        // P: C-layout -> A-layout via wave-private LDS
        for (int r = 0; r < 4; r++)
            for (int j = 0; j < 4; j++)
                sP[w][(quad * 4 + r) * LDK + j * 16 + c15] = (bf16)sfr[j][r];
        __syncthreads();

        // O += P V   (A = P [16q][64key], B = V^T [d][key])
        const bf16* pp = sP[w] + c15 * LDK + quad * 8;
        bf16x8 ap0 = *(const bf16x8*)pp;
        bf16x8 ap1 = *(const bf16x8*)(pp + 32);
        for (int j = 0; j < 4; j++) {
            const bf16* vtp = sVt + (j * 16 + c15) * LDK + quad * 8;
            bf16x8 bv0 = *(const bf16x8*)vtp;
            bf16x8 bv1 = *(const bf16x8*)(vtp + 32);
            o_acc[j] = __builtin_amdgcn_mfma_f32_16x16x32_bf16(ap0, bv0, o_acc[j], 0, 0, 0);
            o_acc[j] = __builtin_amdgcn_mfma_f32_16x16x32_bf16(ap1, bv1, o_acc[j], 0, 0, 0);
        }
        __syncthreads();
    }

    // epilogue: O/l, accumulate branches into fp32 out
    for (int r = 0; r < 4; r++) {
        float inv = 1.0f / l_i[r];
        int row = n0 + w * 16 + quad * 4 + r;
        float* op = out + ((size_t)batch * N_ + row) * D_ + colOff;
        for (int j = 0; j < 4; j++) {
            float v = o_acc[j][r] * inv;
            int col = j * 16 + c15;
            if (accumulate) op[col] += v;
            else            op[col] = v;
        }
    }
}

// ---------------------------------------------------------------------------
extern "C" void kernel_launch(void* const* d_in, const int* in_sizes, int n_in,
                              void* d_out, int out_size, void* d_ws, size_t ws_size,
                              hipStream_t stream) {
    const float* x  = (const float*)d_in[0];
    const float* wq = (const float*)d_in[1];
    const float* bq = (const float*)d_in[2];
    const float* wk = (const float*)d_in[3];
    const float* bk = (const float*)d_in[4];
    const float* wv = (const float*)d_in[5];
    const float* bv = (const float*)d_in[6];
    float* out = (float*)d_out;

    // workspace layout (~61 MB total)
    char* ws = (char*)d_ws;
    bf16*  xbf = (bf16*)ws;                                   // 12,582,912 B
    bf16*  wbf = (bf16*)(ws + 12582912);                      // 10,616,832 B
    float* sc  = (float*)(ws + 12582912 + 10616832);          //     65,536 B
    bf16*  qkv = (bf16*)(ws + 12582912 + 10616832 + 65536);   // 37,748,736 B (one branch's q,k,v)

    hipLaunchKernelGGL(prep_x, dim3(M_), dim3(256), 0, stream, x, xbf, sc);
    hipLaunchKernelGGL(prep_w, dim3((9 * WSZ_ / 4) / 256), dim3(256), 0, stream, wq, wk, wv, wbf);
    for (int br = 0; br < 3; br++) {
        hipLaunchKernelGGL(gemm_qkv, dim3(D_ / BN, M_ / BM, 3), dim3(256), 0, stream,
                           xbf, wbf, bq, bk, bv, sc, br, qkv);
        hipLaunchKernelGGL(attn, dim3(N_ / 64, B_ * H_), dim3(256), 0, stream,
                           qkv, out, br);
    }
}